// Round 1
// baseline (427.116 us; speedup 1.0000x reference)
//
#include <hip/hip_runtime.h>
#include <math.h>

#define B_  256
#define N_  1024
#define D_  512
#define H_  2048
#define O_  512
#define M4  (4 * B_)    // 1024 rows in aggr
#define M12 (12 * B_)   // 3072 rows in scale_concat

// ---------------------------------------------------------------------------
// Kernel 1: masked aggregation over N.
// grid = B * (D/256) = 512 blocks, 256 threads. Thread owns one (b, d).
// Single pass: sum, sumsq, max, min, cnt. mean = sum/cnt, std = sqrt(E[x^2]-mean^2).
// ---------------------------------------------------------------------------
__global__ __launch_bounds__(256) void agg_kernel(const float* __restrict__ x,
                                                  const float* __restrict__ mask,
                                                  float* __restrict__ aggr) {
    const int b = blockIdx.x >> 1;
    const int d = ((blockIdx.x & 1) << 8) + threadIdx.x;
    const float* xp = x + ((size_t)b * N_) * D_ + d;
    const float* mp = mask + (size_t)b * N_;

    float sum = 0.f, sumsq = 0.f, cnt = 0.f;
    float mx = -INFINITY, mn = INFINITY;

    #pragma unroll 4
    for (int n = 0; n < N_; ++n) {
        float m = mp[n];                 // uniform across block -> scalar load
        float v = xp[(size_t)n * D_];
        sum   += v * m;
        sumsq += v * v * m;
        cnt   += m;
        if (m > 0.f) {
            mx = fmaxf(mx, v);
            mn = fminf(mn, v);
        }
    }
    float mean = sum / cnt;
    float var  = sumsq / cnt - mean * mean;
    var = fmaxf(var, 0.f);
    float stdv = sqrtf(var);

    aggr[(size_t)(0 * B_ + b) * D_ + d] = mean;
    aggr[(size_t)(1 * B_ + b) * D_ + d] = mx;
    aggr[(size_t)(2 * B_ + b) * D_ + d] = mn;
    aggr[(size_t)(3 * B_ + b) * D_ + d] = stdv;
}

// ---------------------------------------------------------------------------
// Kernel 2: delta = sum(unpadded) + 1; per-row scales for the 12B rows.
// scale[r] = 1 (r<1024) | logu[r-1024]/delta | delta/logu[r-2048]
// One block, 1024 threads.
// ---------------------------------------------------------------------------
__global__ __launch_bounds__(1024) void scale_kernel(const float* __restrict__ unpadded,
                                                     float* __restrict__ scale) {
    __shared__ float red[1024];
    const int t = threadIdx.x;
    float u = unpadded[t];
    red[t] = u;
    __syncthreads();
    for (int s = 512; s > 0; s >>= 1) {
        if (t < s) red[t] += red[t + s];
        __syncthreads();
    }
    float delta = red[0] + 1.0f;
    float logu  = logf(u + 1.0f);
    scale[t]            = 1.0f;
    scale[M4 + t]       = logu / delta;
    scale[2 * M4 + t]   = delta / logu;
}

// ---------------------------------------------------------------------------
// Kernels 3/4: fp32 tiled GEMM, C = op(A*scale) @ B + bias [, ReLU].
// 64x64 tile, BK=16, 256 threads, 4x4 per thread.
// SCALE_A: A has only M4 physical rows; logical row r reads A[r & (M4-1)] * scale[r].
// ---------------------------------------------------------------------------
template<bool SCALE_A, bool RELU>
__global__ __launch_bounds__(256) void gemm64(const float* __restrict__ A,
                                              const float* __restrict__ Bw,
                                              const float* __restrict__ bias,
                                              const float* __restrict__ rscale,
                                              float* __restrict__ C,
                                              int M, int N, int K) {
    __shared__ float As[16][72];   // stored transposed: As[k][m]
    __shared__ float Bs[16][72];   // Bs[k][n]

    const int t  = threadIdx.x;
    const int tx = t & 15;         // 0..15 -> 4 cols each
    const int ty = t >> 4;         // 0..15 -> 4 rows each
    const int row0 = blockIdx.y << 6;
    const int col0 = blockIdx.x << 6;

    // A staging: each thread loads one float4 per k-step.
    const int ar   = t >> 2;        // 0..63 (tile row)
    const int ak4  = (t & 3) << 2;  // 0,4,8,12 (k offset)
    const int garow = row0 + ar;
    float ascale = 1.0f;
    const float* Ap;
    if (SCALE_A) {
        ascale = rscale[garow];
        Ap = A + (size_t)(garow & (M4 - 1)) * K + ak4;
    } else {
        Ap = A + (size_t)garow * K + ak4;
    }
    // B staging: each thread loads one float4 per k-step.
    const int bk  = t >> 4;         // 0..15 (k row)
    const int bc4 = (t & 15) << 2;  // 0..60 (col offset)
    const float* Bp = Bw + (size_t)bk * N + col0 + bc4;

    float acc[4][4] = {};

    for (int k0 = 0; k0 < K; k0 += 16) {
        float4 av = *(const float4*)(Ap + k0);
        float4 bv = *(const float4*)(Bp + (size_t)k0 * N);
        if (SCALE_A) { av.x *= ascale; av.y *= ascale; av.z *= ascale; av.w *= ascale; }
        __syncthreads();   // previous iteration's reads must finish before overwrite
        As[ak4 + 0][ar] = av.x;
        As[ak4 + 1][ar] = av.y;
        As[ak4 + 2][ar] = av.z;
        As[ak4 + 3][ar] = av.w;
        *(float4*)(&Bs[bk][bc4]) = bv;
        __syncthreads();

        #pragma unroll
        for (int k = 0; k < 16; ++k) {
            float4 aq = *(const float4*)(&As[k][ty << 2]);
            float4 bq = *(const float4*)(&Bs[k][tx << 2]);
            acc[0][0] += aq.x * bq.x; acc[0][1] += aq.x * bq.y;
            acc[0][2] += aq.x * bq.z; acc[0][3] += aq.x * bq.w;
            acc[1][0] += aq.y * bq.x; acc[1][1] += aq.y * bq.y;
            acc[1][2] += aq.y * bq.z; acc[1][3] += aq.y * bq.w;
            acc[2][0] += aq.z * bq.x; acc[2][1] += aq.z * bq.y;
            acc[2][2] += aq.z * bq.z; acc[2][3] += aq.z * bq.w;
            acc[3][0] += aq.w * bq.x; acc[3][1] += aq.w * bq.y;
            acc[3][2] += aq.w * bq.z; acc[3][3] += aq.w * bq.w;
        }
    }

    #pragma unroll
    for (int i = 0; i < 4; ++i) {
        const int row = row0 + (ty << 2) + i;
        const int col = col0 + (tx << 2);
        float4 o;
        o.x = acc[i][0] + bias[col + 0];
        o.y = acc[i][1] + bias[col + 1];
        o.z = acc[i][2] + bias[col + 2];
        o.w = acc[i][3] + bias[col + 3];
        if (RELU) {
            o.x = fmaxf(o.x, 0.f); o.y = fmaxf(o.y, 0.f);
            o.z = fmaxf(o.z, 0.f); o.w = fmaxf(o.w, 0.f);
        }
        *(float4*)(&C[(size_t)row * N + col]) = o;
    }
}

// ---------------------------------------------------------------------------
extern "C" void kernel_launch(void* const* d_in, const int* in_sizes, int n_in,
                              void* d_out, int out_size, void* d_ws, size_t ws_size,
                              hipStream_t stream) {
    const float* x        = (const float*)d_in[0];
    const float* mask     = (const float*)d_in[1];
    const float* unpadded = (const float*)d_in[2];
    const float* W1       = (const float*)d_in[3];
    const float* b1       = (const float*)d_in[4];
    const float* W2       = (const float*)d_in[5];
    const float* b2       = (const float*)d_in[6];
    float* out = (float*)d_out;

    float* ws    = (float*)d_ws;
    float* aggr  = ws;                          // M4 * D = 1024*512 floats (2 MB)
    float* scale = ws + (size_t)M4 * D_;        // 3072 floats
    float* h     = ws + (size_t)M4 * D_ + 4096; // M12 * H = 3072*2048 floats (24 MB)

    // 1. aggregation
    agg_kernel<<<B_ * (D_ / 256), 256, 0, stream>>>(x, mask, aggr);

    // 2. scales
    scale_kernel<<<1, 1024, 0, stream>>>(unpadded, scale);

    // 3. h = relu(scale_concat @ W1 + b1)   [3072 x 2048]
    gemm64<true, true><<<dim3(H_ / 64, M12 / 64), 256, 0, stream>>>(
        aggr, W1, b1, scale, h, M12, H_, D_);

    // 4. out = h @ W2 + b2                  [3072 x 512]
    gemm64<false, false><<<dim3(O_ / 64, M12 / 64), 256, 0, stream>>>(
        h, W2, b2, nullptr, out, M12, O_, H_);
}

// Round 2
// 185.548 us; speedup vs baseline: 2.3019x; 2.3019x over previous
//
#include <hip/hip_runtime.h>
#include <math.h>
#include <stdint.h>

#define B_  256
#define N_  1024
#define D_  512
#define H_  2048
#define O_  512
#define M4  (4 * B_)    // 1024 rows in aggr
#define M12 (12 * B_)   // 3072 rows in scale_concat
#define NS_ 4           // N-chunks for aggregation

typedef __attribute__((ext_vector_type(8))) short short8;
typedef __attribute__((ext_vector_type(4))) float f32x4;

// bf16 round-to-nearest-even
__device__ inline unsigned short f2bf(float f) {
    union { float f; uint32_t u; } v; v.f = f;
    uint32_t r = v.u + 0x7FFFu + ((v.u >> 16) & 1u);
    return (unsigned short)(r >> 16);
}

// async global->LDS 16B (CK-style addrspace casts; LDS dest must be the
// wave-uniform base: HW adds lane*16)
__device__ inline void load_lds16(const void* g, void* l) {
    typedef const __attribute__((address_space(1))) uint32_t* gp_t;
    typedef __attribute__((address_space(3))) uint32_t* lp_t;
    __builtin_amdgcn_global_load_lds((gp_t)(uintptr_t)g, (lp_t)(uint32_t)(uintptr_t)l,
                                     16, 0, 0);
}

// ---------------------------------------------------------------------------
// Aggregation pass 1: per (b, n-chunk) partial sum/sumsq/max/min (+cnt).
// grid (B, NS), 256 threads; thread owns 2 d's (float2).
// ---------------------------------------------------------------------------
__global__ __launch_bounds__(256) void agg_partial(const float* __restrict__ x,
                                                   const float* __restrict__ mask,
                                                   float* __restrict__ part,
                                                   float* __restrict__ cntp) {
    const int b = blockIdx.x;
    const int c = blockIdx.y;
    const int t = threadIdx.x;
    const int rows = N_ / NS_;           // 256

    const float2* xp = (const float2*)(x + ((size_t)b * N_ + (size_t)c * rows) * D_) + t;
    const float* mp  = mask + (size_t)b * N_ + (size_t)c * rows;

    float2 sum = {0.f, 0.f}, sq = {0.f, 0.f};
    float2 mx = {-INFINITY, -INFINITY}, mn = {INFINITY, INFINITY};
    float cnt = 0.f;

    #pragma unroll 4
    for (int n = 0; n < rows; ++n) {
        float  m = mp[n];
        float2 v = xp[(size_t)n * (D_ / 2)];
        sum.x += v.x * m;  sum.y += v.y * m;
        sq.x  += v.x * v.x * m;  sq.y += v.y * v.y * m;
        cnt   += m;
        bool um = m > 0.f;
        mx.x = um ? fmaxf(mx.x, v.x) : mx.x;
        mx.y = um ? fmaxf(mx.y, v.y) : mx.y;
        mn.x = um ? fminf(mn.x, v.x) : mn.x;
        mn.y = um ? fminf(mn.y, v.y) : mn.y;
    }

    const size_t SS = (size_t)B_ * NS_ * D_;                 // stat stride
    const size_t pi = ((size_t)(b * NS_ + c)) * D_ + 2 * t;
    *(float2*)(part + 0 * SS + pi) = sum;
    *(float2*)(part + 1 * SS + pi) = sq;
    *(float2*)(part + 2 * SS + pi) = mx;
    *(float2*)(part + 3 * SS + pi) = mn;
    if (t == 0) cntp[b * NS_ + c] = cnt;
}

// ---------------------------------------------------------------------------
// Aggregation pass 2: combine NS chunks, derive mean/max/min/std, emit bf16.
// grid B, 256 threads, thread owns 2 d's.
// ---------------------------------------------------------------------------
__global__ __launch_bounds__(256) void agg_final(const float* __restrict__ part,
                                                 const float* __restrict__ cntp,
                                                 unsigned short* __restrict__ aggr) {
    const int b = blockIdx.x;
    const int t = threadIdx.x;
    const int d = 2 * t;

    float cnt = 0.f;
    #pragma unroll
    for (int c = 0; c < NS_; ++c) cnt += cntp[b * NS_ + c];

    const size_t SS = (size_t)B_ * NS_ * D_;
    float2 sum = {0.f, 0.f}, sq = {0.f, 0.f};
    float2 mx = {-INFINITY, -INFINITY}, mn = {INFINITY, INFINITY};
    #pragma unroll
    for (int c = 0; c < NS_; ++c) {
        const size_t pi = ((size_t)(b * NS_ + c)) * D_ + d;
        float2 s  = *(const float2*)(part + 0 * SS + pi);
        float2 q  = *(const float2*)(part + 1 * SS + pi);
        float2 vx = *(const float2*)(part + 2 * SS + pi);
        float2 vn = *(const float2*)(part + 3 * SS + pi);
        sum.x += s.x; sum.y += s.y;
        sq.x  += q.x; sq.y  += q.y;
        mx.x = fmaxf(mx.x, vx.x); mx.y = fmaxf(mx.y, vx.y);
        mn.x = fminf(mn.x, vn.x); mn.y = fminf(mn.y, vn.y);
    }
    float2 mean = {sum.x / cnt, sum.y / cnt};
    float2 var  = {fmaxf(sq.x / cnt - mean.x * mean.x, 0.f),
                   fmaxf(sq.y / cnt - mean.y * mean.y, 0.f)};
    float2 stdv = {sqrtf(var.x), sqrtf(var.y)};

    ushort2 o;
    o.x = f2bf(mean.x); o.y = f2bf(mean.y);
    *(ushort2*)(aggr + (size_t)(0 * B_ + b) * D_ + d) = o;
    o.x = f2bf(mx.x);   o.y = f2bf(mx.y);
    *(ushort2*)(aggr + (size_t)(1 * B_ + b) * D_ + d) = o;
    o.x = f2bf(mn.x);   o.y = f2bf(mn.y);
    *(ushort2*)(aggr + (size_t)(2 * B_ + b) * D_ + d) = o;
    o.x = f2bf(stdv.x); o.y = f2bf(stdv.y);
    *(ushort2*)(aggr + (size_t)(3 * B_ + b) * D_ + d) = o;
}

// ---------------------------------------------------------------------------
// Per-row scales. delta = sum(unpadded) + 1 (scalar). One block, 1024 threads.
// ---------------------------------------------------------------------------
__global__ __launch_bounds__(1024) void scale_kernel(const float* __restrict__ unpadded,
                                                     float* __restrict__ scale) {
    __shared__ float red[1024];
    const int t = threadIdx.x;
    float u = unpadded[t];
    red[t] = u;
    __syncthreads();
    for (int s = 512; s > 0; s >>= 1) {
        if (t < s) red[t] += red[t + s];
        __syncthreads();
    }
    float delta = red[0] + 1.0f;
    float logu  = logf(u + 1.0f);
    scale[t]            = 1.0f;
    scale[M4 + t]       = logu / delta;
    scale[2 * M4 + t]   = delta / logu;
}

// ---------------------------------------------------------------------------
// fp32 [R x C] -> bf16 transposed [C x R], 32x32 LDS tiles.
// ---------------------------------------------------------------------------
__global__ __launch_bounds__(256) void convert_transpose(const float* __restrict__ in,
                                                         unsigned short* __restrict__ out,
                                                         int R, int C) {
    __shared__ float tile[32][33];
    const int t  = threadIdx.x;
    const int r0 = blockIdx.y << 5;
    const int c0 = blockIdx.x << 5;
    const int tr = t >> 3;
    const int tc = (t & 7) << 2;

    float4 v = *(const float4*)(in + (size_t)(r0 + tr) * C + c0 + tc);
    tile[tr][tc + 0] = v.x; tile[tr][tc + 1] = v.y;
    tile[tr][tc + 2] = v.z; tile[tr][tc + 3] = v.w;
    __syncthreads();

    ushort4 o;
    o.x = f2bf(tile[tc + 0][tr]);
    o.y = f2bf(tile[tc + 1][tr]);
    o.z = f2bf(tile[tc + 2][tr]);
    o.w = f2bf(tile[tc + 3][tr]);
    *(ushort4*)(out + (size_t)(c0 + tr) * R + r0 + tc) = o;
}

// ---------------------------------------------------------------------------
// bf16 MFMA GEMM: C[M x N] = A[M x K] @ Bt[N x K]^T (+ bias).
// 256 threads = 4 waves (2x2), BK=32, m97-style 2-barrier loop,
// global_load_lds width 16, k-contiguous ds_read_b128 fragments.
// ---------------------------------------------------------------------------
template<int TM, int TN, bool BIAS>
__global__ __launch_bounds__(256) void gemm_mfma(const unsigned short* __restrict__ A,
                                                 const unsigned short* __restrict__ Bt,
                                                 const float* __restrict__ bias,
                                                 float* __restrict__ C,
                                                 int M, int N, int K) {
    constexpr int WTM = TM / 2, WTN = TN / 2;
    constexpr int FM = WTM / 16, FN = WTN / 16;
    __shared__ unsigned short As[TM * 32];
    __shared__ unsigned short Bs[TN * 32];

    const int t    = threadIdx.x;
    const int wave = t >> 6;
    const int lane = t & 63;
    const int wm   = wave >> 1, wn = wave & 1;

    const int row0 = blockIdx.y * TM;
    const int col0 = blockIdx.x * TN;

    // staging geometry: wave writes 16 rows (1KB) per load op, LDS linear.
    const int srow = wave * 16 + (lane >> 2);   // tile row within 64-row round
    const int scol = (lane & 3) * 8;            // k offset (bf16 elems)

    f32x4 acc[FM][FN] = {};

    const int rl = lane & 15;
    const int g8 = (lane >> 4) * 8;

    for (int k0 = 0; k0 < K; k0 += 32) {
        __syncthreads();   // all waves done reading previous tile
        #pragma unroll
        for (int q = 0; q < TM / 64; ++q) {
            const unsigned short* g = A + (size_t)(row0 + q * 64 + srow) * K + k0 + scol;
            load_lds16(g, As + (q * 64 + wave * 16) * 32);
        }
        #pragma unroll
        for (int q = 0; q < TN / 64; ++q) {
            const unsigned short* g = Bt + (size_t)(col0 + q * 64 + srow) * K + k0 + scol;
            load_lds16(g, Bs + (q * 64 + wave * 16) * 32);
        }
        __syncthreads();   // compiler drains vmcnt before barrier

        short8 av[FM], bv[FN];
        #pragma unroll
        for (int i = 0; i < FM; ++i)
            av[i] = *(const short8*)(As + (wm * WTM + i * 16 + rl) * 32 + g8);
        #pragma unroll
        for (int j = 0; j < FN; ++j)
            bv[j] = *(const short8*)(Bs + (wn * WTN + j * 16 + rl) * 32 + g8);
        #pragma unroll
        for (int i = 0; i < FM; ++i)
            #pragma unroll
            for (int j = 0; j < FN; ++j)
                acc[i][j] = __builtin_amdgcn_mfma_f32_16x16x32_bf16(av[i], bv[j], acc[i][j], 0, 0, 0);
    }

    // C/D layout: col = lane&15, row = (lane>>4)*4 + reg  [m89/m91 verified]
    #pragma unroll
    for (int i = 0; i < FM; ++i) {
        #pragma unroll
        for (int j = 0; j < FN; ++j) {
            const int col = col0 + wn * WTN + j * 16 + (lane & 15);
            const float bb = BIAS ? bias[col] : 0.f;
            #pragma unroll
            for (int v = 0; v < 4; ++v) {
                const int row = row0 + wm * WTM + i * 16 + (lane >> 4) * 4 + v;
                C[(size_t)row * N + col] = acc[i][j][v] + bb;
            }
        }
    }
}

// ---------------------------------------------------------------------------
// h[r] = bf16(relu(scale[r] * Z[r mod 1024] + b1)), r in [0, 3072)
// ---------------------------------------------------------------------------
__global__ __launch_bounds__(256) void expand_kernel(const float* __restrict__ Z,
                                                     const float* __restrict__ scale,
                                                     const float* __restrict__ b1,
                                                     unsigned short* __restrict__ h) {
    const int r = blockIdx.x;
    const int j = blockIdx.y * 1024 + threadIdx.x * 4;
    const float s = scale[r];
    float4 z  = *(const float4*)(Z + (size_t)(r & (M4 - 1)) * H_ + j);
    float4 bb = *(const float4*)(b1 + j);
    ushort4 o;
    o.x = f2bf(fmaxf(s * z.x + bb.x, 0.f));
    o.y = f2bf(fmaxf(s * z.y + bb.y, 0.f));
    o.z = f2bf(fmaxf(s * z.z + bb.z, 0.f));
    o.w = f2bf(fmaxf(s * z.w + bb.w, 0.f));
    *(ushort4*)(h + (size_t)r * H_ + j) = o;
}

// ---------------------------------------------------------------------------
extern "C" void kernel_launch(void* const* d_in, const int* in_sizes, int n_in,
                              void* d_out, int out_size, void* d_ws, size_t ws_size,
                              hipStream_t stream) {
    const float* x        = (const float*)d_in[0];
    const float* mask     = (const float*)d_in[1];
    const float* unpadded = (const float*)d_in[2];
    const float* W1       = (const float*)d_in[3];
    const float* b1       = (const float*)d_in[4];
    const float* W2       = (const float*)d_in[5];
    const float* b2       = (const float*)d_in[6];
    float* out = (float*)d_out;

    float* ws = (float*)d_ws;
    // fp32 region (float offsets)
    float* part  = ws;                               // 4 * 524288 = 2,097,152
    float* cntp  = ws + 2097152;                     // 1024
    float* scale = ws + 2098176;                     // 3072
    float* Z     = ws + 2101248;                     // 1024*2048 = 2,097,152
    // bf16 region
    unsigned short* bfw  = (unsigned short*)(ws + 4198400);
    unsigned short* W1t  = bfw;                      // 2048*512
    unsigned short* W2t  = bfw + 1048576;            // 512*2048
    unsigned short* aggr = bfw + 2097152;            // 1024*512
    unsigned short* h    = bfw + 2621440;            // 3072*2048

    // weight convert+transpose to [N x K] bf16
    convert_transpose<<<dim3(H_ / 32, D_ / 32), 256, 0, stream>>>(W1, W1t, D_, H_);
    convert_transpose<<<dim3(O_ / 32, H_ / 32), 256, 0, stream>>>(W2, W2t, H_, O_);

    // aggregation
    agg_partial<<<dim3(B_, NS_), 256, 0, stream>>>(x, mask, part, cntp);
    agg_final<<<B_, 256, 0, stream>>>(part, cntp, aggr);

    // scales
    scale_kernel<<<1, 1024, 0, stream>>>(unpadded, scale);

    // Z = aggr @ W1   [1024 x 2048], K=512
    gemm_mfma<64, 128, false><<<dim3(H_ / 128, M4 / 64), 256, 0, stream>>>(
        aggr, W1t, nullptr, Z, M4, H_, D_);

    // h = bf16(relu(scale * Z + b1))  [3072 x 2048]
    expand_kernel<<<dim3(M12, H_ / 1024), 256, 0, stream>>>(Z, scale, b1, h);

    // out = h @ W2 + b2  [3072 x 512], K=2048
    gemm_mfma<128, 64, true><<<dim3(O_ / 64, M12 / 128), 256, 0, stream>>>(
        h, W2t, b2, out, M12, O_, H_);
}

// Round 3
// 177.730 us; speedup vs baseline: 2.4032x; 1.0440x over previous
//
#include <hip/hip_runtime.h>
#include <math.h>
#include <stdint.h>

#define B_  256
#define N_  1024
#define D_  512
#define H_  2048
#define O_  512
#define M4  (4 * B_)    // 1024 rows in aggr
#define M12 (12 * B_)   // 3072 rows in scale_concat
#define NCH 8           // partial chunks per b (4 n-chunks x 2 row-parity)

typedef __attribute__((ext_vector_type(8))) short short8;
typedef __attribute__((ext_vector_type(4))) float f32x4;

// bf16 round-to-nearest-even
__device__ inline unsigned short f2bf(float f) {
    union { float f; uint32_t u; } v; v.f = f;
    uint32_t r = v.u + 0x7FFFu + ((v.u >> 16) & 1u);
    return (unsigned short)(r >> 16);
}

// async global->LDS 16B. LDS dest = wave-uniform base (HW adds lane*16).
__device__ inline void load_lds16(const void* g, void* l) {
    typedef const __attribute__((address_space(1))) uint32_t* gp_t;
    typedef __attribute__((address_space(3))) uint32_t* lp_t;
    __builtin_amdgcn_global_load_lds((gp_t)(uintptr_t)g, (lp_t)(uint32_t)(uintptr_t)l,
                                     16, 0, 0);
}

// ---------------------------------------------------------------------------
// K1 mega-kernel. Block roles by blockIdx.x:
//   [0,1024)      masked aggregation partials (b = id>>2, n-chunk = id&3)
//   [1024,2048)   W1 [512x2048] -> bf16 W1t [2048x512] (transposed)
//   [2048,3072)   W2 [2048x512] -> bf16 W2t [512x2048]
//   3072          delta + per-row scales
// ---------------------------------------------------------------------------
__device__ void conv_tile(const float* __restrict__ in, unsigned short* __restrict__ out,
                          int R, int C, int bx, int by, float* tile /*32*33*/) {
    const int t  = threadIdx.x;
    const int r0 = by << 5;
    const int c0 = bx << 5;
    const int tr = t >> 3;
    const int tc = (t & 7) << 2;

    float4 v = *(const float4*)(in + (size_t)(r0 + tr) * C + c0 + tc);
    tile[tr * 33 + tc + 0] = v.x; tile[tr * 33 + tc + 1] = v.y;
    tile[tr * 33 + tc + 2] = v.z; tile[tr * 33 + tc + 3] = v.w;
    __syncthreads();

    ushort4 o;
    o.x = f2bf(tile[(tc + 0) * 33 + tr]);
    o.y = f2bf(tile[(tc + 1) * 33 + tr]);
    o.z = f2bf(tile[(tc + 2) * 33 + tr]);
    o.w = f2bf(tile[(tc + 3) * 33 + tr]);
    *(ushort4*)(out + (size_t)(c0 + tr) * R + r0 + tc) = o;
}

__global__ __launch_bounds__(256) void k1_mega(const float* __restrict__ x,
                                               const float* __restrict__ mask,
                                               const float* __restrict__ W1,
                                               const float* __restrict__ W2,
                                               const float* __restrict__ unpadded,
                                               float* __restrict__ part,
                                               float* __restrict__ cntp,
                                               unsigned short* __restrict__ W1t,
                                               unsigned short* __restrict__ W2t,
                                               float* __restrict__ scale) {
    __shared__ float smem[32 * 33];
    const int id = blockIdx.x;
    const int t  = threadIdx.x;

    if (id < 1024) {
        // ---- aggregation partials: float4, 2-row-parity split ----
        const int b    = id >> 2;
        const int c    = id & 3;
        const int half = t >> 7;              // 0/1: even/odd rows
        const int d4   = (t & 127) << 2;      // d offset (4 floats)
        const float* base = x + ((size_t)b * N_ + (size_t)c * 256) * D_ + d4;
        const float* mp   = mask + (size_t)b * N_ + (size_t)c * 256;

        float4 sum = {0.f,0.f,0.f,0.f}, sq = {0.f,0.f,0.f,0.f};
        float4 mx = {-INFINITY,-INFINITY,-INFINITY,-INFINITY};
        float4 mn = { INFINITY, INFINITY, INFINITY, INFINITY};
        float cnt = 0.f;

        #pragma unroll 4
        for (int n = half; n < 256; n += 2) {
            float  m = mp[n];
            float4 v = *(const float4*)(base + (size_t)n * D_);
            sum.x = fmaf(v.x, m, sum.x); sum.y = fmaf(v.y, m, sum.y);
            sum.z = fmaf(v.z, m, sum.z); sum.w = fmaf(v.w, m, sum.w);
            sq.x  = fmaf(v.x * v.x, m, sq.x); sq.y = fmaf(v.y * v.y, m, sq.y);
            sq.z  = fmaf(v.z * v.z, m, sq.z); sq.w = fmaf(v.w * v.w, m, sq.w);
            cnt  += m;
            bool um = m > 0.f;
            mx.x = um ? fmaxf(mx.x, v.x) : mx.x; mx.y = um ? fmaxf(mx.y, v.y) : mx.y;
            mx.z = um ? fmaxf(mx.z, v.z) : mx.z; mx.w = um ? fmaxf(mx.w, v.w) : mx.w;
            mn.x = um ? fminf(mn.x, v.x) : mn.x; mn.y = um ? fminf(mn.y, v.y) : mn.y;
            mn.z = um ? fminf(mn.z, v.z) : mn.z; mn.w = um ? fminf(mn.w, v.w) : mn.w;
        }

        const int ch = c * 2 + half;
        const size_t SS = (size_t)B_ * NCH * D_;
        const size_t pi = ((size_t)(b * NCH + ch)) * D_ + d4;
        *(float4*)(part + 0 * SS + pi) = sum;
        *(float4*)(part + 1 * SS + pi) = sq;
        *(float4*)(part + 2 * SS + pi) = mx;
        *(float4*)(part + 3 * SS + pi) = mn;
        if ((t & 127) == 0) cntp[b * NCH + ch] = cnt;
    } else if (id < 2048) {
        const int tid = id - 1024;              // W1: grid (64, 16)
        conv_tile(W1, W1t, D_, H_, tid & 63, tid >> 6, smem);
    } else if (id < 3072) {
        const int tid = id - 2048;              // W2: grid (16, 64)
        conv_tile(W2, W2t, H_, O_, tid & 15, tid >> 4, smem);
    } else {
        // ---- scales: delta = sum(unpadded)+1 ----
        float4 u4 = *(const float4*)(unpadded + t * 4);
        smem[t] = u4.x + u4.y + u4.z + u4.w;
        __syncthreads();
        for (int s = 128; s > 0; s >>= 1) {
            if (t < s) smem[t] += smem[t + s];
            __syncthreads();
        }
        const float delta = smem[0] + 1.0f;
        float uu[4] = {u4.x, u4.y, u4.z, u4.w};
        #pragma unroll
        for (int j = 0; j < 4; ++j) {
            const int i = t * 4 + j;
            const float logu = logf(uu[j] + 1.0f);
            scale[i]          = 1.0f;
            scale[M4 + i]     = logu / delta;
            scale[2 * M4 + i] = delta / logu;
        }
    }
}

// ---------------------------------------------------------------------------
// K2: combine NCH chunks, derive mean/max/min/std, emit bf16 aggr [1024x512].
// ---------------------------------------------------------------------------
__global__ __launch_bounds__(256) void agg_final(const float* __restrict__ part,
                                                 const float* __restrict__ cntp,
                                                 unsigned short* __restrict__ aggr) {
    const int b = blockIdx.x;
    const int t = threadIdx.x;
    const int d = 2 * t;

    float cnt = 0.f;
    #pragma unroll
    for (int c = 0; c < NCH; ++c) cnt += cntp[b * NCH + c];

    const size_t SS = (size_t)B_ * NCH * D_;
    float2 sum = {0.f, 0.f}, sq = {0.f, 0.f};
    float2 mx = {-INFINITY, -INFINITY}, mn = {INFINITY, INFINITY};
    #pragma unroll
    for (int c = 0; c < NCH; ++c) {
        const size_t pi = ((size_t)(b * NCH + c)) * D_ + d;
        float2 s  = *(const float2*)(part + 0 * SS + pi);
        float2 q  = *(const float2*)(part + 1 * SS + pi);
        float2 vx = *(const float2*)(part + 2 * SS + pi);
        float2 vn = *(const float2*)(part + 3 * SS + pi);
        sum.x += s.x; sum.y += s.y;
        sq.x  += q.x; sq.y  += q.y;
        mx.x = fmaxf(mx.x, vx.x); mx.y = fmaxf(mx.y, vx.y);
        mn.x = fminf(mn.x, vn.x); mn.y = fminf(mn.y, vn.y);
    }
    float2 mean = {sum.x / cnt, sum.y / cnt};
    float2 var  = {fmaxf(sq.x / cnt - mean.x * mean.x, 0.f),
                   fmaxf(sq.y / cnt - mean.y * mean.y, 0.f)};

    ushort2 o;
    o.x = f2bf(mean.x); o.y = f2bf(mean.y);
    *(ushort2*)(aggr + (size_t)(0 * B_ + b) * D_ + d) = o;
    o.x = f2bf(mx.x);   o.y = f2bf(mx.y);
    *(ushort2*)(aggr + (size_t)(1 * B_ + b) * D_ + d) = o;
    o.x = f2bf(mn.x);   o.y = f2bf(mn.y);
    *(ushort2*)(aggr + (size_t)(2 * B_ + b) * D_ + d) = o;
    o.x = f2bf(sqrtf(var.x)); o.y = f2bf(sqrtf(var.y));
    *(ushort2*)(aggr + (size_t)(3 * B_ + b) * D_ + d) = o;
}

// ---------------------------------------------------------------------------
// K3: Z = aggr @ W1  [1024 x 2048], K=512. bf16 MFMA, tile 64x128, 4 waves.
// ---------------------------------------------------------------------------
__global__ __launch_bounds__(256) void gemm1(const unsigned short* __restrict__ A,
                                             const unsigned short* __restrict__ Bt,
                                             float* __restrict__ C) {
    constexpr int TM = 64, TN = 128;
    constexpr int WTM = 32, WTN = 64;
    constexpr int FM = 2, FN = 4;
    __shared__ unsigned short As[TM * 32];
    __shared__ unsigned short Bs[TN * 32];

    const int t    = threadIdx.x;
    const int wave = t >> 6;
    const int lane = t & 63;
    const int wm   = wave >> 1, wn = wave & 1;
    const int row0 = blockIdx.y * TM;
    const int col0 = blockIdx.x * TN;

    const int srow = wave * 16 + (lane >> 2);
    const int scol = (lane & 3) * 8;

    f32x4 acc[FM][FN] = {};
    const int rl = lane & 15;
    const int g8 = (lane >> 4) * 8;

    for (int k0 = 0; k0 < D_; k0 += 32) {
        __syncthreads();
        load_lds16(A + (size_t)(row0 + srow) * D_ + k0 + scol, As + (wave * 16) * 32);
        #pragma unroll
        for (int q = 0; q < 2; ++q)
            load_lds16(Bt + (size_t)(col0 + q * 64 + srow) * D_ + k0 + scol,
                       Bs + (q * 64 + wave * 16) * 32);
        __syncthreads();

        short8 av[FM], bv[FN];
        #pragma unroll
        for (int i = 0; i < FM; ++i)
            av[i] = *(const short8*)(As + (wm * WTM + i * 16 + rl) * 32 + g8);
        #pragma unroll
        for (int j = 0; j < FN; ++j)
            bv[j] = *(const short8*)(Bs + (wn * WTN + j * 16 + rl) * 32 + g8);
        #pragma unroll
        for (int i = 0; i < FM; ++i)
            #pragma unroll
            for (int j = 0; j < FN; ++j)
                acc[i][j] = __builtin_amdgcn_mfma_f32_16x16x32_bf16(av[i], bv[j], acc[i][j], 0, 0, 0);
    }

    #pragma unroll
    for (int i = 0; i < FM; ++i)
        #pragma unroll
        for (int j = 0; j < FN; ++j) {
            const int col = col0 + wn * WTN + j * 16 + rl;
            #pragma unroll
            for (int v = 0; v < 4; ++v) {
                const int row = row0 + wm * WTM + i * 16 + (lane >> 4) * 4 + v;
                C[(size_t)row * H_ + col] = acc[i][j][v];
            }
        }
}

// ---------------------------------------------------------------------------
// K4: out = relu(scale*Z + b1) @ W2 + b2  [3072 x 512], K=2048.
// A-tile computed on the fly (expand fused into staging). Tile 64x64, 4 waves.
// ---------------------------------------------------------------------------
__global__ __launch_bounds__(256) void gemm2_fused(const float* __restrict__ Z,
                                                   const float* __restrict__ scale,
                                                   const float* __restrict__ b1,
                                                   const unsigned short* __restrict__ W2t,
                                                   const float* __restrict__ b2,
                                                   float* __restrict__ out) {
    __shared__ unsigned short As[64 * 32];
    __shared__ unsigned short Bs[64 * 32];

    const int t    = threadIdx.x;
    const int wave = t >> 6;
    const int lane = t & 63;
    const int wm   = wave >> 1, wn = wave & 1;
    const int row0 = blockIdx.y * 64;
    const int col0 = blockIdx.x * 64;

    // A staging: thread t produces 8 bf16 of row arow, k-chunk ach.
    const int arow = t >> 2;
    const int ach  = (t & 3) * 8;
    const float s  = scale[row0 + arow];
    const float* Zrow = Z + (size_t)((row0 + arow) & (M4 - 1)) * H_;

    // B staging: global_load_lds, wave stages 16 rows.
    const int srow = wave * 16 + (lane >> 2);
    const int scol = (lane & 3) * 8;
    const unsigned short* Bg = W2t + (size_t)(col0 + srow) * H_ + scol;

    f32x4 acc[2][2] = {};
    const int rl = lane & 15;
    const int g8 = (lane >> 4) * 8;

    for (int k0 = 0; k0 < H_; k0 += 32) {
        // issue A-source loads early (global, no LDS hazard)
        float4 z0 = *(const float4*)(Zrow + k0 + ach);
        float4 z1 = *(const float4*)(Zrow + k0 + ach + 4);
        float4 c0 = *(const float4*)(b1 + k0 + ach);
        float4 c1 = *(const float4*)(b1 + k0 + ach + 4);
        __syncthreads();   // previous tile fully consumed
        load_lds16(Bg + k0, Bs + (wave * 16) * 32);
        short8 hv;
        hv[0] = (short)f2bf(fmaxf(fmaf(s, z0.x, c0.x), 0.f));
        hv[1] = (short)f2bf(fmaxf(fmaf(s, z0.y, c0.y), 0.f));
        hv[2] = (short)f2bf(fmaxf(fmaf(s, z0.z, c0.z), 0.f));
        hv[3] = (short)f2bf(fmaxf(fmaf(s, z0.w, c0.w), 0.f));
        hv[4] = (short)f2bf(fmaxf(fmaf(s, z1.x, c1.x), 0.f));
        hv[5] = (short)f2bf(fmaxf(fmaf(s, z1.y, c1.y), 0.f));
        hv[6] = (short)f2bf(fmaxf(fmaf(s, z1.z, c1.z), 0.f));
        hv[7] = (short)f2bf(fmaxf(fmaf(s, z1.w, c1.w), 0.f));
        *(short8*)(As + arow * 32 + ach) = hv;   // linear: byte off = t*16, conflict-free
        __syncthreads();   // drains vmcnt (B) + lgkm (A)

        short8 av[2], bv[2];
        #pragma unroll
        for (int i = 0; i < 2; ++i)
            av[i] = *(const short8*)(As + (wm * 32 + i * 16 + rl) * 32 + g8);
        #pragma unroll
        for (int j = 0; j < 2; ++j)
            bv[j] = *(const short8*)(Bs + (wn * 32 + j * 16 + rl) * 32 + g8);
        #pragma unroll
        for (int i = 0; i < 2; ++i)
            #pragma unroll
            for (int j = 0; j < 2; ++j)
                acc[i][j] = __builtin_amdgcn_mfma_f32_16x16x32_bf16(av[i], bv[j], acc[i][j], 0, 0, 0);
    }

    #pragma unroll
    for (int i = 0; i < 2; ++i)
        #pragma unroll
        for (int j = 0; j < 2; ++j) {
            const int col = col0 + wn * 32 + j * 16 + rl;
            const float bb = b2[col];
            #pragma unroll
            for (int v = 0; v < 4; ++v) {
                const int row = row0 + wm * 32 + i * 16 + (lane >> 4) * 4 + v;
                out[(size_t)row * O_ + col] = acc[i][j][v] + bb;
            }
        }
}

// ---------------------------------------------------------------------------
extern "C" void kernel_launch(void* const* d_in, const int* in_sizes, int n_in,
                              void* d_out, int out_size, void* d_ws, size_t ws_size,
                              hipStream_t stream) {
    const float* x        = (const float*)d_in[0];
    const float* mask     = (const float*)d_in[1];
    const float* unpadded = (const float*)d_in[2];
    const float* W1       = (const float*)d_in[3];
    const float* b1       = (const float*)d_in[4];
    const float* W2       = (const float*)d_in[5];
    const float* b2       = (const float*)d_in[6];
    float* out = (float*)d_out;

    float* ws = (float*)d_ws;
    float* part  = ws;                        // 4 * 1,048,576
    float* cntp  = ws + 4194304;              // 2048
    float* scale = ws + 4196352;              // 3072
    float* Z     = ws + 4199424;              // 1024*2048
    unsigned short* bfw  = (unsigned short*)(ws + 6296576);
    unsigned short* W1t  = bfw;               // 2048*512
    unsigned short* W2t  = bfw + 1048576;     // 512*2048
    unsigned short* aggr = bfw + 2097152;     // 1024*512

    k1_mega<<<3073, 256, 0, stream>>>(x, mask, W1, W2, unpadded,
                                      part, cntp, W1t, W2t, scale);
    agg_final<<<B_, 256, 0, stream>>>(part, cntp, aggr);
    gemm1<<<dim3(H_ / 128, M4 / 64), 256, 0, stream>>>(aggr, W1t, Z);
    gemm2_fused<<<dim3(O_ / 64, M12 / 64), 256, 0, stream>>>(Z, scale, b1, W2t, b2, out);
}

// Round 4
// 160.696 us; speedup vs baseline: 2.6579x; 1.1060x over previous
//
#include <hip/hip_runtime.h>
#include <hip/hip_bf16.h>
#include <math.h>
#include <stdint.h>

#define B_  256
#define N_  1024
#define D_  512
#define H_  2048
#define O_  512
#define M4  (4 * B_)    // 1024 rows in aggr
#define M12 (12 * B_)   // 3072 rows in scale_concat
#define NCH 8           // partial chunks per b

typedef __attribute__((ext_vector_type(8))) short short8;
typedef __attribute__((ext_vector_type(4))) float f32x4;
typedef unsigned short ushort_t;

// packed f32x2 -> bf16x2 (RNE); compiler emits v_cvt_pk_bf16_f32
__device__ inline uint32_t pkbf(float a, float b) {
    union { __hip_bfloat162 h; uint32_t u; } cv;
    cv.h = __float22bfloat162_rn(float2{a, b});
    return cv.u;
}
__device__ inline ushort_t f2bf(float f) {
    union { float f; uint32_t u; } v; v.f = f;
    uint32_t r = v.u + 0x7FFFu + ((v.u >> 16) & 1u);
    return (ushort_t)(r >> 16);
}

// async global->LDS 16B. LDS dest = wave-uniform base (HW adds lane*16).
__device__ inline void load_lds16(const void* g, void* l) {
    typedef const __attribute__((address_space(1))) uint32_t* gp_t;
    typedef __attribute__((address_space(3))) uint32_t* lp_t;
    __builtin_amdgcn_global_load_lds((gp_t)(uintptr_t)g, (lp_t)(uint32_t)(uintptr_t)l,
                                     16, 0, 0);
}

// ---------------------------------------------------------------------------
// K1 mega-kernel: agg partials [0,1024) | W1 conv [1024,2048) |
//                 W2 conv [2048,3072) | scales 3072
// ---------------------------------------------------------------------------
__device__ void conv_tile(const float* __restrict__ in, ushort_t* __restrict__ out,
                          int R, int C, int bx, int by, float* tile /*32*33*/) {
    const int t  = threadIdx.x;
    const int r0 = by << 5;
    const int c0 = bx << 5;
    const int tr = t >> 3;
    const int tc = (t & 7) << 2;

    float4 v = *(const float4*)(in + (size_t)(r0 + tr) * C + c0 + tc);
    tile[tr * 33 + tc + 0] = v.x; tile[tr * 33 + tc + 1] = v.y;
    tile[tr * 33 + tc + 2] = v.z; tile[tr * 33 + tc + 3] = v.w;
    __syncthreads();

    union { uint32_t u[2]; ushort4 us; } o;
    o.u[0] = pkbf(tile[(tc + 0) * 33 + tr], tile[(tc + 1) * 33 + tr]);
    o.u[1] = pkbf(tile[(tc + 2) * 33 + tr], tile[(tc + 3) * 33 + tr]);
    *(ushort4*)(out + (size_t)(c0 + tr) * R + r0 + tc) = o.us;
}

__global__ __launch_bounds__(256) void k1_mega(const float* __restrict__ x,
                                               const float* __restrict__ mask,
                                               const float* __restrict__ W1,
                                               const float* __restrict__ W2,
                                               const float* __restrict__ unpadded,
                                               float* __restrict__ part,
                                               float* __restrict__ cntp,
                                               ushort_t* __restrict__ W1t,
                                               ushort_t* __restrict__ W2t,
                                               float* __restrict__ scale) {
    __shared__ float smem[32 * 33];
    const int id = blockIdx.x;
    const int t  = threadIdx.x;

    if (id < 1024) {
        const int b    = id >> 2;
        const int c    = id & 3;
        const int half = t >> 7;
        const int d4   = (t & 127) << 2;
        const float* base = x + ((size_t)b * N_ + (size_t)c * 256) * D_ + d4;
        const float* mp   = mask + (size_t)b * N_ + (size_t)c * 256;

        float4 sum = {0.f,0.f,0.f,0.f}, sq = {0.f,0.f,0.f,0.f};
        float4 mx = {-INFINITY,-INFINITY,-INFINITY,-INFINITY};
        float4 mn = { INFINITY, INFINITY, INFINITY, INFINITY};
        float cnt = 0.f;

        #pragma unroll 4
        for (int n = half; n < 256; n += 2) {
            float  m = mp[n];
            float4 v = *(const float4*)(base + (size_t)n * D_);
            sum.x = fmaf(v.x, m, sum.x); sum.y = fmaf(v.y, m, sum.y);
            sum.z = fmaf(v.z, m, sum.z); sum.w = fmaf(v.w, m, sum.w);
            sq.x  = fmaf(v.x * v.x, m, sq.x); sq.y = fmaf(v.y * v.y, m, sq.y);
            sq.z  = fmaf(v.z * v.z, m, sq.z); sq.w = fmaf(v.w * v.w, m, sq.w);
            cnt  += m;
            bool um = m > 0.f;
            mx.x = um ? fmaxf(mx.x, v.x) : mx.x; mx.y = um ? fmaxf(mx.y, v.y) : mx.y;
            mx.z = um ? fmaxf(mx.z, v.z) : mx.z; mx.w = um ? fmaxf(mx.w, v.w) : mx.w;
            mn.x = um ? fminf(mn.x, v.x) : mn.x; mn.y = um ? fminf(mn.y, v.y) : mn.y;
            mn.z = um ? fminf(mn.z, v.z) : mn.z; mn.w = um ? fminf(mn.w, v.w) : mn.w;
        }

        const int ch = c * 2 + half;
        const size_t SS = (size_t)B_ * NCH * D_;
        const size_t pi = ((size_t)(b * NCH + ch)) * D_ + d4;
        *(float4*)(part + 0 * SS + pi) = sum;
        *(float4*)(part + 1 * SS + pi) = sq;
        *(float4*)(part + 2 * SS + pi) = mx;
        *(float4*)(part + 3 * SS + pi) = mn;
        if ((t & 127) == 0) cntp[b * NCH + ch] = cnt;
    } else if (id < 2048) {
        const int tid = id - 1024;
        conv_tile(W1, W1t, D_, H_, tid & 63, tid >> 6, smem);
    } else if (id < 3072) {
        const int tid = id - 2048;
        conv_tile(W2, W2t, H_, O_, tid & 15, tid >> 4, smem);
    } else {
        float4 u4 = *(const float4*)(unpadded + t * 4);
        smem[t] = u4.x + u4.y + u4.z + u4.w;
        __syncthreads();
        for (int s = 128; s > 0; s >>= 1) {
            if (t < s) smem[t] += smem[t + s];
            __syncthreads();
        }
        const float delta = smem[0] + 1.0f;
        float uu[4] = {u4.x, u4.y, u4.z, u4.w};
        #pragma unroll
        for (int j = 0; j < 4; ++j) {
            const int i = t * 4 + j;
            const float logu = logf(uu[j] + 1.0f);
            scale[i]          = 1.0f;
            scale[M4 + i]     = logu / delta;
            scale[2 * M4 + i] = delta / logu;
        }
    }
}

// ---------------------------------------------------------------------------
// K2: combine NCH chunks -> bf16 aggr [1024 x 512].
// ---------------------------------------------------------------------------
__global__ __launch_bounds__(256) void agg_final(const float* __restrict__ part,
                                                 const float* __restrict__ cntp,
                                                 ushort_t* __restrict__ aggr) {
    const int b = blockIdx.x;
    const int t = threadIdx.x;
    const int d = 2 * t;

    float cnt = 0.f;
    #pragma unroll
    for (int c = 0; c < NCH; ++c) cnt += cntp[b * NCH + c];

    const size_t SS = (size_t)B_ * NCH * D_;
    float2 sum = {0.f, 0.f}, sq = {0.f, 0.f};
    float2 mx = {-INFINITY, -INFINITY}, mn = {INFINITY, INFINITY};
    #pragma unroll
    for (int c = 0; c < NCH; ++c) {
        const size_t pi = ((size_t)(b * NCH + c)) * D_ + d;
        float2 s  = *(const float2*)(part + 0 * SS + pi);
        float2 q  = *(const float2*)(part + 1 * SS + pi);
        float2 vx = *(const float2*)(part + 2 * SS + pi);
        float2 vn = *(const float2*)(part + 3 * SS + pi);
        sum.x += s.x; sum.y += s.y;
        sq.x  += q.x; sq.y  += q.y;
        mx.x = fmaxf(mx.x, vx.x); mx.y = fmaxf(mx.y, vx.y);
        mn.x = fminf(mn.x, vn.x); mn.y = fminf(mn.y, vn.y);
    }
    float2 mean = {sum.x / cnt, sum.y / cnt};
    float2 var  = {fmaxf(sq.x / cnt - mean.x * mean.x, 0.f),
                   fmaxf(sq.y / cnt - mean.y * mean.y, 0.f)};

    *(uint32_t*)(aggr + (size_t)(0 * B_ + b) * D_ + d) = pkbf(mean.x, mean.y);
    *(uint32_t*)(aggr + (size_t)(1 * B_ + b) * D_ + d) = pkbf(mx.x, mx.y);
    *(uint32_t*)(aggr + (size_t)(2 * B_ + b) * D_ + d) = pkbf(mn.x, mn.y);
    *(uint32_t*)(aggr + (size_t)(3 * B_ + b) * D_ + d) = pkbf(sqrtf(var.x), sqrtf(var.y));
}

// ---------------------------------------------------------------------------
// K3: Z = aggr @ W1t^T  [1024 x 2048], K=512. Tile 64x64, BK=64, 4 waves.
// LDS rows 128B, slot-XOR swizzle (slot s holds k-slot s^(row&7)), staged via
// pre-swizzled global source for global_load_lds; reads use same XOR.
// ---------------------------------------------------------------------------
__global__ __launch_bounds__(256) void gemm1(const ushort_t* __restrict__ A,
                                             const ushort_t* __restrict__ Bt,
                                             float* __restrict__ C) {
    __shared__ ushort_t As[64 * 64];
    __shared__ ushort_t Bs[64 * 64];

    const int t    = threadIdx.x;
    const int wave = t >> 6;
    const int lane = t & 63;
    const int wm   = wave >> 1, wn = wave & 1;
    const int row0 = blockIdx.y << 6;
    const int col0 = blockIdx.x << 6;

    const int lr  = lane >> 3;                 // staging row within 8-row group
    const int ksw = ((lane & 7) ^ lr) << 3;    // pre-swizzled k elem offset

    const int rl = lane & 15;
    const int hi = lane >> 4;                  // 0..3

    f32x4 acc[2][2] = {};

    for (int k0 = 0; k0 < D_; k0 += 64) {
        __syncthreads();
        #pragma unroll
        for (int q = 0; q < 2; ++q) {
            const int tr = q * 32 + wave * 8;
            load_lds16(A  + (size_t)(row0 + tr + lr) * D_ + k0 + ksw, As + tr * 64);
            load_lds16(Bt + (size_t)(col0 + tr + lr) * D_ + k0 + ksw, Bs + tr * 64);
        }
        __syncthreads();

        short8 av[2][2], bv[2][2];
        #pragma unroll
        for (int i = 0; i < 2; ++i) {
            const int ra = wm * 32 + i * 16 + rl;
            const int rb = wn * 32 + i * 16 + rl;
            #pragma unroll
            for (int k2 = 0; k2 < 2; ++k2) {
                av[i][k2] = *(const short8*)(As + ra * 64 + (((k2 * 4 + hi) ^ (ra & 7)) << 3));
                bv[i][k2] = *(const short8*)(Bs + rb * 64 + (((k2 * 4 + hi) ^ (rb & 7)) << 3));
            }
        }
        #pragma unroll
        for (int i = 0; i < 2; ++i)
            #pragma unroll
            for (int j = 0; j < 2; ++j)
                #pragma unroll
                for (int k2 = 0; k2 < 2; ++k2)
                    acc[i][j] = __builtin_amdgcn_mfma_f32_16x16x32_bf16(av[i][k2], bv[j][k2], acc[i][j], 0, 0, 0);
    }

    #pragma unroll
    for (int i = 0; i < 2; ++i)
        #pragma unroll
        for (int j = 0; j < 2; ++j) {
            const int col = col0 + wn * 32 + j * 16 + rl;
            #pragma unroll
            for (int v = 0; v < 4; ++v) {
                const int row = row0 + wm * 32 + i * 16 + hi * 4 + v;
                C[(size_t)row * H_ + col] = acc[i][j][v];
            }
        }
}

// ---------------------------------------------------------------------------
// K4: out = relu(scale*Z + b1) @ W2t^T + b2  [3072 x 512], K=2048.
// Tile 64x128, BK=64, 8 waves (2x4). A computed on the fly (swizzled ds_write);
// B staged via pre-swizzled global_load_lds.
// ---------------------------------------------------------------------------
__global__ __launch_bounds__(512) void gemm2_fused(const float* __restrict__ Z,
                                                   const float* __restrict__ scale,
                                                   const float* __restrict__ b1,
                                                   const ushort_t* __restrict__ W2t,
                                                   const float* __restrict__ b2,
                                                   float* __restrict__ out) {
    __shared__ ushort_t As[64 * 64];    // 8 KB
    __shared__ ushort_t Bs[128 * 64];   // 16 KB

    const int t    = threadIdx.x;
    const int wave = t >> 6;
    const int lane = t & 63;
    const int wm   = wave >> 2, wn = wave & 3;
    const int row0 = blockIdx.y << 6;
    const int col0 = blockIdx.x << 7;

    // A staging: thread t computes 8 bf16 of row arow, k-slot asi.
    const int arow = t >> 3;
    const int asi  = t & 7;
    const float s  = scale[row0 + arow];
    const float* Zrow = Z + (size_t)((row0 + arow) & (M4 - 1)) * H_ + asi * 8;
    const float* b1p  = b1 + asi * 8;
    ushort_t* Aw = As + arow * 64 + ((asi ^ (arow & 7)) << 3);

    // B staging: pre-swizzled source.
    const int lr  = lane >> 3;
    const int ksw = ((lane & 7) ^ lr) << 3;

    const int rl = lane & 15;
    const int hi = lane >> 4;

    f32x4 acc[2][2] = {};

    for (int k0 = 0; k0 < H_; k0 += 64) {
        float4 z0 = *(const float4*)(Zrow + k0);
        float4 z1 = *(const float4*)(Zrow + k0 + 4);
        float4 c0 = *(const float4*)(b1p + k0);
        float4 c1 = *(const float4*)(b1p + k0 + 4);
        __syncthreads();    // previous tile fully consumed
        #pragma unroll
        for (int q = 0; q < 2; ++q) {
            const int tr = q * 64 + wave * 8;
            load_lds16(W2t + (size_t)(col0 + tr + lr) * H_ + k0 + ksw, Bs + tr * 64);
        }
        union { uint32_t u[4]; short8 s8; } hv;
        hv.u[0] = pkbf(fmaxf(fmaf(s, z0.x, c0.x), 0.f), fmaxf(fmaf(s, z0.y, c0.y), 0.f));
        hv.u[1] = pkbf(fmaxf(fmaf(s, z0.z, c0.z), 0.f), fmaxf(fmaf(s, z0.w, c0.w), 0.f));
        hv.u[2] = pkbf(fmaxf(fmaf(s, z1.x, c1.x), 0.f), fmaxf(fmaf(s, z1.y, c1.y), 0.f));
        hv.u[3] = pkbf(fmaxf(fmaf(s, z1.z, c1.z), 0.f), fmaxf(fmaf(s, z1.w, c1.w), 0.f));
        *(short8*)Aw = hv.s8;
        __syncthreads();    // drains vmcnt (B) + lgkm (A)

        short8 av[2][2], bv[2][2];
        #pragma unroll
        for (int i = 0; i < 2; ++i) {
            const int ra = wm * 32 + i * 16 + rl;
            const int rb = wn * 32 + i * 16 + rl;
            #pragma unroll
            for (int k2 = 0; k2 < 2; ++k2) {
                av[i][k2] = *(const short8*)(As + ra * 64 + (((k2 * 4 + hi) ^ (ra & 7)) << 3));
                bv[i][k2] = *(const short8*)(Bs + rb * 64 + (((k2 * 4 + hi) ^ (rb & 7)) << 3));
            }
        }
        #pragma unroll
        for (int i = 0; i < 2; ++i)
            #pragma unroll
            for (int j = 0; j < 2; ++j)
                #pragma unroll
                for (int k2 = 0; k2 < 2; ++k2)
                    acc[i][j] = __builtin_amdgcn_mfma_f32_16x16x32_bf16(av[i][k2], bv[j][k2], acc[i][j], 0, 0, 0);
    }

    #pragma unroll
    for (int i = 0; i < 2; ++i)
        #pragma unroll
        for (int j = 0; j < 2; ++j) {
            const int col = col0 + wn * 32 + j * 16 + rl;
            const float bb = b2[col];
            #pragma unroll
            for (int v = 0; v < 4; ++v) {
                const int row = row0 + wm * 32 + i * 16 + hi * 4 + v;
                out[(size_t)row * O_ + col] = acc[i][j][v] + bb;
            }
        }
}

// ---------------------------------------------------------------------------
extern "C" void kernel_launch(void* const* d_in, const int* in_sizes, int n_in,
                              void* d_out, int out_size, void* d_ws, size_t ws_size,
                              hipStream_t stream) {
    const float* x        = (const float*)d_in[0];
    const float* mask     = (const float*)d_in[1];
    const float* unpadded = (const float*)d_in[2];
    const float* W1       = (const float*)d_in[3];
    const float* b1       = (const float*)d_in[4];
    const float* W2       = (const float*)d_in[5];
    const float* b2       = (const float*)d_in[6];
    float* out = (float*)d_out;

    float* ws = (float*)d_ws;
    float* part  = ws;                        // 4 * 1,048,576
    float* cntp  = ws + 4194304;              // 2048
    float* scale = ws + 4196352;              // 3072
    float* Z     = ws + 4199424;              // 1024*2048
    ushort_t* bfw  = (ushort_t*)(ws + 6296576);
    ushort_t* W1t  = bfw;                     // 2048*512
    ushort_t* W2t  = bfw + 1048576;           // 512*2048
    ushort_t* aggr = bfw + 2097152;           // 1024*512

    k1_mega<<<3073, 256, 0, stream>>>(x, mask, W1, W2, unpadded,
                                      part, cntp, W1t, W2t, scale);
    agg_final<<<B_, 256, 0, stream>>>(part, cntp, aggr);
    gemm1<<<dim3(H_ / 64, M4 / 64), 256, 0, stream>>>(aggr, W1t, Z);
    gemm2_fused<<<dim3(O_ / 128, M12 / 64), 512, 0, stream>>>(Z, scale, b1, W2t, b2, out);
}

// Round 5
// 157.618 us; speedup vs baseline: 2.7098x; 1.0195x over previous
//
#include <hip/hip_runtime.h>
#include <hip/hip_bf16.h>
#include <math.h>
#include <stdint.h>

#define B_  256
#define N_  1024
#define D_  512
#define H_  2048
#define O_  512
#define M4  (4 * B_)    // 1024 rows in aggr
#define M12 (12 * B_)   // 3072 rows in scale_concat
#define NCH 8           // partial chunks per b

typedef __attribute__((ext_vector_type(8))) short short8;
typedef __attribute__((ext_vector_type(4))) float f32x4;
typedef unsigned short ushort_t;

// packed f32x2 -> bf16x2 (RNE); compiler emits v_cvt_pk_bf16_f32
__device__ inline uint32_t pkbf(float a, float b) {
    union { __hip_bfloat162 h; uint32_t u; } cv;
    cv.h = __float22bfloat162_rn(float2{a, b});
    return cv.u;
}

// async global->LDS 16B. LDS dest = wave-uniform base (HW adds lane*16).
__device__ inline void load_lds16(const void* g, void* l) {
    typedef const __attribute__((address_space(1))) uint32_t* gp_t;
    typedef __attribute__((address_space(3))) uint32_t* lp_t;
    __builtin_amdgcn_global_load_lds((gp_t)(uintptr_t)g, (lp_t)(uint32_t)(uintptr_t)l,
                                     16, 0, 0);
}

// ---------------------------------------------------------------------------
// K1 mega-kernel: agg partials [0,1024) | W1 conv [1024,2048) |
//                 W2 conv [2048,3072) | scales 3072
// ---------------------------------------------------------------------------
__device__ void conv_tile(const float* __restrict__ in, ushort_t* __restrict__ out,
                          int R, int C, int bx, int by, float* tile /*32*33*/) {
    const int t  = threadIdx.x;
    const int r0 = by << 5;
    const int c0 = bx << 5;
    const int tr = t >> 3;
    const int tc = (t & 7) << 2;

    float4 v = *(const float4*)(in + (size_t)(r0 + tr) * C + c0 + tc);
    tile[tr * 33 + tc + 0] = v.x; tile[tr * 33 + tc + 1] = v.y;
    tile[tr * 33 + tc + 2] = v.z; tile[tr * 33 + tc + 3] = v.w;
    __syncthreads();

    union { uint32_t u[2]; ushort4 us; } o;
    o.u[0] = pkbf(tile[(tc + 0) * 33 + tr], tile[(tc + 1) * 33 + tr]);
    o.u[1] = pkbf(tile[(tc + 2) * 33 + tr], tile[(tc + 3) * 33 + tr]);
    *(ushort4*)(out + (size_t)(c0 + tr) * R + r0 + tc) = o.us;
}

__global__ __launch_bounds__(256) void k1_mega(const float* __restrict__ x,
                                               const float* __restrict__ mask,
                                               const float* __restrict__ W1,
                                               const float* __restrict__ W2,
                                               const float* __restrict__ unpadded,
                                               float* __restrict__ part,
                                               float* __restrict__ cntp,
                                               ushort_t* __restrict__ W1t,
                                               ushort_t* __restrict__ W2t,
                                               float* __restrict__ scale) {
    __shared__ float smem[32 * 33];
    const int id = blockIdx.x;
    const int t  = threadIdx.x;

    if (id < 1024) {
        const int b    = id >> 2;
        const int c    = id & 3;
        const int half = t >> 7;
        const int d4   = (t & 127) << 2;
        const float* base = x + ((size_t)b * N_ + (size_t)c * 256) * D_ + d4;
        const float* mp   = mask + (size_t)b * N_ + (size_t)c * 256;

        float4 sum = {0.f,0.f,0.f,0.f}, sq = {0.f,0.f,0.f,0.f};
        float4 mx = {-INFINITY,-INFINITY,-INFINITY,-INFINITY};
        float4 mn = { INFINITY, INFINITY, INFINITY, INFINITY};
        float cnt = 0.f;

        #pragma unroll 4
        for (int n = half; n < 256; n += 2) {
            float  m = mp[n];
            float4 v = *(const float4*)(base + (size_t)n * D_);
            sum.x = fmaf(v.x, m, sum.x); sum.y = fmaf(v.y, m, sum.y);
            sum.z = fmaf(v.z, m, sum.z); sum.w = fmaf(v.w, m, sum.w);
            sq.x  = fmaf(v.x * v.x, m, sq.x); sq.y = fmaf(v.y * v.y, m, sq.y);
            sq.z  = fmaf(v.z * v.z, m, sq.z); sq.w = fmaf(v.w * v.w, m, sq.w);
            cnt  += m;
            bool um = m > 0.f;
            mx.x = um ? fmaxf(mx.x, v.x) : mx.x; mx.y = um ? fmaxf(mx.y, v.y) : mx.y;
            mx.z = um ? fmaxf(mx.z, v.z) : mx.z; mx.w = um ? fmaxf(mx.w, v.w) : mx.w;
            mn.x = um ? fminf(mn.x, v.x) : mn.x; mn.y = um ? fminf(mn.y, v.y) : mn.y;
            mn.z = um ? fminf(mn.z, v.z) : mn.z; mn.w = um ? fminf(mn.w, v.w) : mn.w;
        }

        const int ch = c * 2 + half;
        const size_t SS = (size_t)B_ * NCH * D_;
        const size_t pi = ((size_t)(b * NCH + ch)) * D_ + d4;
        *(float4*)(part + 0 * SS + pi) = sum;
        *(float4*)(part + 1 * SS + pi) = sq;
        *(float4*)(part + 2 * SS + pi) = mx;
        *(float4*)(part + 3 * SS + pi) = mn;
        if ((t & 127) == 0) cntp[b * NCH + ch] = cnt;
    } else if (id < 2048) {
        const int tid = id - 1024;
        conv_tile(W1, W1t, D_, H_, tid & 63, tid >> 6, smem);
    } else if (id < 3072) {
        const int tid = id - 2048;
        conv_tile(W2, W2t, H_, O_, tid & 15, tid >> 4, smem);
    } else {
        float4 u4 = *(const float4*)(unpadded + t * 4);
        smem[t] = u4.x + u4.y + u4.z + u4.w;
        __syncthreads();
        for (int s = 128; s > 0; s >>= 1) {
            if (t < s) smem[t] += smem[t + s];
            __syncthreads();
        }
        const float delta = smem[0] + 1.0f;
        float uu[4] = {u4.x, u4.y, u4.z, u4.w};
        #pragma unroll
        for (int j = 0; j < 4; ++j) {
            const int i = t * 4 + j;
            const float logu = logf(uu[j] + 1.0f);
            scale[i]          = 1.0f;
            scale[M4 + i]     = logu / delta;
            scale[2 * M4 + i] = delta / logu;
        }
    }
}

// ---------------------------------------------------------------------------
// K2: combine NCH chunks -> bf16 aggr [1024 x 512]. 128 thr, float4/thread.
// ---------------------------------------------------------------------------
__global__ __launch_bounds__(128) void agg_final(const float* __restrict__ part,
                                                 const float* __restrict__ cntp,
                                                 ushort_t* __restrict__ aggr) {
    const int b = blockIdx.x;
    const int t = threadIdx.x;
    const int d = 4 * t;

    float cnt = 0.f;
    #pragma unroll
    for (int c = 0; c < NCH; ++c) cnt += cntp[b * NCH + c];

    const size_t SS = (size_t)B_ * NCH * D_;
    float4 sum = {0.f,0.f,0.f,0.f}, sq = {0.f,0.f,0.f,0.f};
    float4 mx = {-INFINITY,-INFINITY,-INFINITY,-INFINITY};
    float4 mn = { INFINITY, INFINITY, INFINITY, INFINITY};
    #pragma unroll
    for (int c = 0; c < NCH; ++c) {
        const size_t pi = ((size_t)(b * NCH + c)) * D_ + d;
        float4 s  = *(const float4*)(part + 0 * SS + pi);
        float4 q  = *(const float4*)(part + 1 * SS + pi);
        float4 vx = *(const float4*)(part + 2 * SS + pi);
        float4 vn = *(const float4*)(part + 3 * SS + pi);
        sum.x += s.x; sum.y += s.y; sum.z += s.z; sum.w += s.w;
        sq.x  += q.x; sq.y  += q.y; sq.z  += q.z; sq.w  += q.w;
        mx.x = fmaxf(mx.x, vx.x); mx.y = fmaxf(mx.y, vx.y);
        mx.z = fmaxf(mx.z, vx.z); mx.w = fmaxf(mx.w, vx.w);
        mn.x = fminf(mn.x, vn.x); mn.y = fminf(mn.y, vn.y);
        mn.z = fminf(mn.z, vn.z); mn.w = fminf(mn.w, vn.w);
    }
    const float ic = 1.f / cnt;
    float4 mean = {sum.x * ic, sum.y * ic, sum.z * ic, sum.w * ic};
    float4 var  = {fmaxf(sq.x * ic - mean.x * mean.x, 0.f),
                   fmaxf(sq.y * ic - mean.y * mean.y, 0.f),
                   fmaxf(sq.z * ic - mean.z * mean.z, 0.f),
                   fmaxf(sq.w * ic - mean.w * mean.w, 0.f)};

    union { uint32_t u[2]; ushort4 us; } o;
    o.u[0] = pkbf(mean.x, mean.y); o.u[1] = pkbf(mean.z, mean.w);
    *(ushort4*)(aggr + (size_t)(0 * B_ + b) * D_ + d) = o.us;
    o.u[0] = pkbf(mx.x, mx.y); o.u[1] = pkbf(mx.z, mx.w);
    *(ushort4*)(aggr + (size_t)(1 * B_ + b) * D_ + d) = o.us;
    o.u[0] = pkbf(mn.x, mn.y); o.u[1] = pkbf(mn.z, mn.w);
    *(ushort4*)(aggr + (size_t)(2 * B_ + b) * D_ + d) = o.us;
    o.u[0] = pkbf(sqrtf(var.x), sqrtf(var.y)); o.u[1] = pkbf(sqrtf(var.z), sqrtf(var.w));
    *(ushort4*)(aggr + (size_t)(3 * B_ + b) * D_ + d) = o.us;
}

// ---------------------------------------------------------------------------
// K3: Z = aggr @ W1t^T  [1024 x 2048], K=512. Tile 64x64, BK=64, 4 waves.
// 2-phase double-buffered pipeline: one vmcnt-drain barrier per K-tile.
// Slot-XOR swizzle via pre-swizzled global source; reads use same XOR.
// ---------------------------------------------------------------------------
__global__ __launch_bounds__(256) void gemm1(const ushort_t* __restrict__ A,
                                             const ushort_t* __restrict__ Bt,
                                             float* __restrict__ C) {
    __shared__ ushort_t As0[64 * 64], As1[64 * 64];
    __shared__ ushort_t Bs0[64 * 64], Bs1[64 * 64];

    const int t    = threadIdx.x;
    const int wave = t >> 6;
    const int lane = t & 63;
    const int wm   = wave >> 1, wn = wave & 1;
    const int row0 = blockIdx.y << 6;
    const int col0 = blockIdx.x << 6;

    const int lr  = lane >> 3;
    const int ksw = ((lane & 7) ^ lr) << 3;

    const int rl = lane & 15;
    const int hi = lane >> 4;

    // per-wave staging bases (q in {0,1} -> rows q*32 + wave*8 + lr)
    const ushort_t* Ag0 = A  + (size_t)(row0 + wave * 8 + lr) * D_ + ksw;
    const ushort_t* Ag1 = A  + (size_t)(row0 + 32 + wave * 8 + lr) * D_ + ksw;
    const ushort_t* Bg0 = Bt + (size_t)(col0 + wave * 8 + lr) * D_ + ksw;
    const ushort_t* Bg1 = Bt + (size_t)(col0 + 32 + wave * 8 + lr) * D_ + ksw;
    const int ld0 = (wave * 8) * 64;
    const int ld1 = (32 + wave * 8) * 64;

    f32x4 acc[2][2] = {};

    ushort_t* Ac = As0; ushort_t* An = As1;
    ushort_t* Bc = Bs0; ushort_t* Bn = Bs1;

    // prologue: stage tile 0
    load_lds16(Ag0, Ac + ld0); load_lds16(Ag1, Ac + ld1);
    load_lds16(Bg0, Bc + ld0); load_lds16(Bg1, Bc + ld1);
    __syncthreads();

    for (int tt = 0; tt < D_ / 64; ++tt) {
        const int k1 = (tt + 1) * 64;
        if (tt + 1 < D_ / 64) {
            load_lds16(Ag0 + k1, An + ld0); load_lds16(Ag1 + k1, An + ld1);
            load_lds16(Bg0 + k1, Bn + ld0); load_lds16(Bg1 + k1, Bn + ld1);
        }
        short8 av[2][2], bv[2][2];
        #pragma unroll
        for (int i = 0; i < 2; ++i) {
            const int ra = wm * 32 + i * 16 + rl;
            const int rb = wn * 32 + i * 16 + rl;
            #pragma unroll
            for (int k2 = 0; k2 < 2; ++k2) {
                av[i][k2] = *(const short8*)(Ac + ra * 64 + (((k2 * 4 + hi) ^ (ra & 7)) << 3));
                bv[i][k2] = *(const short8*)(Bc + rb * 64 + (((k2 * 4 + hi) ^ (rb & 7)) << 3));
            }
        }
        #pragma unroll
        for (int i = 0; i < 2; ++i)
            #pragma unroll
            for (int j = 0; j < 2; ++j)
                #pragma unroll
                for (int k2 = 0; k2 < 2; ++k2)
                    acc[i][j] = __builtin_amdgcn_mfma_f32_16x16x32_bf16(av[i][k2], bv[j][k2], acc[i][j], 0, 0, 0);
        __syncthreads();   // drains vmcnt: next tile resident; also guards buffer reuse
        ushort_t* tp;
        tp = Ac; Ac = An; An = tp;
        tp = Bc; Bc = Bn; Bn = tp;
    }

    #pragma unroll
    for (int i = 0; i < 2; ++i)
        #pragma unroll
        for (int j = 0; j < 2; ++j) {
            const int col = col0 + wn * 32 + j * 16 + rl;
            #pragma unroll
            for (int v = 0; v < 4; ++v) {
                const int row = row0 + wm * 32 + i * 16 + hi * 4 + v;
                C[(size_t)row * H_ + col] = acc[i][j][v];
            }
        }
}

// ---------------------------------------------------------------------------
// K4: out = relu(scale*Z + b1) @ W2t^T + b2  [3072 x 512], K=2048.
// Tile 64x128, BK=64, 8 waves. 2-phase pipeline: prefetch B (glds) and Z/b1
// (regs) for tile t+1 during tile t's MFMAs; pack+ds_write A(t+1) after.
// ---------------------------------------------------------------------------
__global__ __launch_bounds__(512) void gemm2_fused(const float* __restrict__ Z,
                                                   const float* __restrict__ scale,
                                                   const float* __restrict__ b1,
                                                   const ushort_t* __restrict__ W2t,
                                                   const float* __restrict__ b2,
                                                   float* __restrict__ out) {
    __shared__ ushort_t As0[64 * 64],  As1[64 * 64];    // 16 KB
    __shared__ ushort_t Bs0[128 * 64], Bs1[128 * 64];   // 32 KB

    const int t    = threadIdx.x;
    const int wave = t >> 6;
    const int lane = t & 63;
    const int wm   = wave >> 2, wn = wave & 3;
    const int row0 = blockIdx.y << 6;
    const int col0 = blockIdx.x << 7;

    // A staging: thread t computes 8 bf16 of row arow, k-slot asi.
    const int arow = t >> 3;
    const int asi  = t & 7;
    const float s  = scale[row0 + arow];
    const float* Zrow = Z + (size_t)((row0 + arow) & (M4 - 1)) * H_ + asi * 8;
    const float* b1p  = b1 + asi * 8;
    const int awoff = arow * 64 + ((asi ^ (arow & 7)) << 3);

    // B staging: pre-swizzled source, wave stages 8 rows per glds.
    const int lr  = lane >> 3;
    const int ksw = ((lane & 7) ^ lr) << 3;
    const ushort_t* Bg0 = W2t + (size_t)(col0 + wave * 8 + lr) * H_ + ksw;
    const ushort_t* Bg1 = W2t + (size_t)(col0 + 64 + wave * 8 + lr) * H_ + ksw;
    const int ld0 = (wave * 8) * 64;
    const int ld1 = (64 + wave * 8) * 64;

    const int rl = lane & 15;
    const int hi = lane >> 4;

    f32x4 acc[2][2] = {};

    ushort_t* Ac = As0; ushort_t* An = As1;
    ushort_t* Bc = Bs0; ushort_t* Bn = Bs1;

    // prologue: stage tile 0 (B via glds; A packed from Z)
    {
        load_lds16(Bg0, Bc + ld0); load_lds16(Bg1, Bc + ld1);
        float4 z0 = *(const float4*)(Zrow);
        float4 z1 = *(const float4*)(Zrow + 4);
        float4 c0 = *(const float4*)(b1p);
        float4 c1 = *(const float4*)(b1p + 4);
        union { uint32_t u[4]; short8 s8; } hv;
        hv.u[0] = pkbf(fmaxf(fmaf(s, z0.x, c0.x), 0.f), fmaxf(fmaf(s, z0.y, c0.y), 0.f));
        hv.u[1] = pkbf(fmaxf(fmaf(s, z0.z, c0.z), 0.f), fmaxf(fmaf(s, z0.w, c0.w), 0.f));
        hv.u[2] = pkbf(fmaxf(fmaf(s, z1.x, c1.x), 0.f), fmaxf(fmaf(s, z1.y, c1.y), 0.f));
        hv.u[3] = pkbf(fmaxf(fmaf(s, z1.z, c1.z), 0.f), fmaxf(fmaf(s, z1.w, c1.w), 0.f));
        *(short8*)(Ac + awoff) = hv.s8;
        __syncthreads();
    }

    for (int tt = 0; tt < H_ / 64; ++tt) {
        const int k1 = (tt + 1) * 64;
        const bool more = (tt + 1 < H_ / 64);
        float4 z0, z1, c0, c1;
        if (more) {
            load_lds16(Bg0 + k1, Bn + ld0); load_lds16(Bg1 + k1, Bn + ld1);
            z0 = *(const float4*)(Zrow + k1);
            z1 = *(const float4*)(Zrow + k1 + 4);
            c0 = *(const float4*)(b1p + k1);
            c1 = *(const float4*)(b1p + k1 + 4);
        }

        short8 av[2][2], bv[2][2];
        #pragma unroll
        for (int i = 0; i < 2; ++i) {
            const int ra = wm * 32 + i * 16 + rl;
            const int rb = wn * 32 + i * 16 + rl;
            #pragma unroll
            for (int k2 = 0; k2 < 2; ++k2) {
                av[i][k2] = *(const short8*)(Ac + ra * 64 + (((k2 * 4 + hi) ^ (ra & 7)) << 3));
                bv[i][k2] = *(const short8*)(Bc + rb * 64 + (((k2 * 4 + hi) ^ (rb & 7)) << 3));
            }
        }
        #pragma unroll
        for (int i = 0; i < 2; ++i)
            #pragma unroll
            for (int j = 0; j < 2; ++j)
                #pragma unroll
                for (int k2 = 0; k2 < 2; ++k2)
                    acc[i][j] = __builtin_amdgcn_mfma_f32_16x16x32_bf16(av[i][k2], bv[j][k2], acc[i][j], 0, 0, 0);

        if (more) {
            union { uint32_t u[4]; short8 s8; } hv;
            hv.u[0] = pkbf(fmaxf(fmaf(s, z0.x, c0.x), 0.f), fmaxf(fmaf(s, z0.y, c0.y), 0.f));
            hv.u[1] = pkbf(fmaxf(fmaf(s, z0.z, c0.z), 0.f), fmaxf(fmaf(s, z0.w, c0.w), 0.f));
            hv.u[2] = pkbf(fmaxf(fmaf(s, z1.x, c1.x), 0.f), fmaxf(fmaf(s, z1.y, c1.y), 0.f));
            hv.u[3] = pkbf(fmaxf(fmaf(s, z1.z, c1.z), 0.f), fmaxf(fmaf(s, z1.w, c1.w), 0.f));
            *(short8*)(An + awoff) = hv.s8;
        }
        __syncthreads();   // one drain per K-tile; glds latency hidden by MFMAs
        ushort_t* tp;
        tp = Ac; Ac = An; An = tp;
        tp = Bc; Bc = Bn; Bn = tp;
    }

    #pragma unroll
    for (int i = 0; i < 2; ++i)
        #pragma unroll
        for (int j = 0; j < 2; ++j) {
            const int col = col0 + wn * 32 + j * 16 + rl;
            const float bb = b2[col];
            #pragma unroll
            for (int v = 0; v < 4; ++v) {
                const int row = row0 + wm * 32 + i * 16 + hi * 4 + v;
                out[(size_t)row * O_ + col] = acc[i][j][v] + bb;
            }
        }
}

// ---------------------------------------------------------------------------
extern "C" void kernel_launch(void* const* d_in, const int* in_sizes, int n_in,
                              void* d_out, int out_size, void* d_ws, size_t ws_size,
                              hipStream_t stream) {
    const float* x        = (const float*)d_in[0];
    const float* mask     = (const float*)d_in[1];
    const float* unpadded = (const float*)d_in[2];
    const float* W1       = (const float*)d_in[3];
    const float* b1       = (const float*)d_in[4];
    const float* W2       = (const float*)d_in[5];
    const float* b2       = (const float*)d_in[6];
    float* out = (float*)d_out;

    float* ws = (float*)d_ws;
    float* part  = ws;                        // 4 * 1,048,576
    float* cntp  = ws + 4194304;              // 2048
    float* scale = ws + 4196352;              // 3072
    float* Z     = ws + 4199424;              // 1024*2048
    ushort_t* bfw  = (ushort_t*)(ws + 6296576);
    ushort_t* W1t  = bfw;                     // 2048*512
    ushort_t* W2t  = bfw + 1048576;           // 512*2048
    ushort_t* aggr = bfw + 2097152;           // 1024*512

    k1_mega<<<3073, 256, 0, stream>>>(x, mask, W1, W2, unpadded,
                                      part, cntp, W1t, W2t, scale);
    agg_final<<<B_, 128, 0, stream>>>(part, cntp, aggr);
    gemm1<<<dim3(H_ / 64, M4 / 64), 256, 0, stream>>>(aggr, W1t, Z);
    gemm2_fused<<<dim3(O_ / 128, M12 / 64), 512, 0, stream>>>(Z, scale, b1, W2t, b2, out);
}